// Round 1
// baseline (456.459 us; speedup 1.0000x reference)
//
#include <hip/hip_runtime.h>

// PortfolioGenerator: B=16384 rows of S=2048 fp32 scores.
// Per row: top-256 softmax scattered -> long_weights, bottom-256 softmax of
// (1 - s) scattered -> short_weights (== softmax(-s) by shift invariance),
// plus clipped short_ratio. One block per row; exact rank-256 threshold via
// 4-pass 8-bit LDS radix select on sortable keys; tie-stable like jax top_k.

#define NT   256
#define SDIM 2048
#define KSEL 256u

__device__ __forceinline__ unsigned f2key(float f) {
    unsigned u = __float_as_uint(f);
    // monotonic map: larger float -> larger unsigned
    return (u & 0x80000000u) ? ~u : (u | 0x80000000u);
}

// scan[b] = sum_{j>=b} cnt[REV ? 255-j : j], executed by wave 0 (t<64).
template <bool REV>
__device__ __forceinline__ void suffix_scan_wave(const unsigned* cnt,
                                                 unsigned* scan, int t) {
    if (t < 64) {
        int b = t << 2;
        unsigned c0 = cnt[REV ? 255 - b : b];
        unsigned c1 = cnt[REV ? 254 - b : b + 1];
        unsigned c2 = cnt[REV ? 253 - b : b + 2];
        unsigned c3 = cnt[REV ? 252 - b : b + 3];
        unsigned s3 = c3;
        unsigned s2 = c2 + s3;
        unsigned s1 = c1 + s2;
        unsigned s0 = c0 + s1;
        unsigned run = s0;
#pragma unroll
        for (int off = 1; off < 64; off <<= 1) {
            unsigned x = __shfl_down(run, off);
            if (t + off < 64) run += x;
        }
        unsigned excl = run - s0;  // sum over lanes > t
        scan[b]     = excl + s0;
        scan[b + 1] = excl + s1;
        scan[b + 2] = excl + s2;
        scan[b + 3] = excl + s3;
    }
}

__global__ void __launch_bounds__(NT) portfolio_kernel(
    const float* __restrict__ scores, const float* __restrict__ short_ratio,
    float* __restrict__ out_long, float* __restrict__ out_short,
    float* __restrict__ out_sr) {
    __shared__ float    s_vals[SDIM];
    __shared__ unsigned s_hist1[256];   // pass-1 histogram (kept for both dirs)
    __shared__ unsigned s_hist2[256];   // refinement histogram
    __shared__ unsigned s_scan[257];    // suffix sums; [256] == 0 sentinel
    __shared__ unsigned s_selbin, s_selk, s_seleq;
    __shared__ float    s_redf[8];
    __shared__ float    s_rowmax, s_rowmin, s_invZW, s_invZL;

    const int    t    = threadIdx.x;
    const int    row  = blockIdx.x;
    const size_t base = (size_t)row * SDIM;

    // ---- load: thread t owns elems [4t..4t+3] and [1024+4t..1024+4t+3] ----
    const float4* rp = (const float4*)(scores + base);
    float4 a0 = rp[t];
    float4 a1 = rp[t + NT];
    float v[8] = {a0.x, a0.y, a0.z, a0.w, a1.x, a1.y, a1.z, a1.w};
    ((float4*)s_vals)[t]      = a0;
    ((float4*)s_vals)[t + NT] = a1;

    unsigned key[8];
#pragma unroll
    for (int j = 0; j < 8; ++j) key[j] = f2key(v[j]);

    s_hist1[t] = 0;
    if (t == 0) s_scan[256] = 0;
    __syncthreads();
#pragma unroll
    for (int j = 0; j < 8; ++j) atomicAdd(&s_hist1[key[j] >> 24], 1u);

    // local + wave max/min (folded before the histogram barrier)
    float lmax = v[0], lmin = v[0];
#pragma unroll
    for (int j = 1; j < 8; ++j) {
        lmax = fmaxf(lmax, v[j]);
        lmin = fminf(lmin, v[j]);
    }
#pragma unroll
    for (int off = 32; off; off >>= 1) {
        lmax = fmaxf(lmax, __shfl_down(lmax, off));
        lmin = fminf(lmin, __shfl_down(lmin, off));
    }
    const int wave = t >> 6, lane = t & 63;
    if (lane == 0) {
        s_redf[wave]     = lmax;
        s_redf[4 + wave] = lmin;
    }
    __syncthreads();  // hist1 done, reductions staged
    if (t == 0) {
        s_rowmax = fmaxf(fmaxf(s_redf[0], s_redf[1]), fmaxf(s_redf[2], s_redf[3]));
        s_rowmin = fminf(fminf(s_redf[4], s_redf[5]), fminf(s_redf[6], s_redf[7]));
    }

    // ---- radix select, dir 0 = winners (desc on key), dir 1 = losers ------
    unsigned thr[2], need[2], eqc[2];
    for (int dir = 0; dir < 2; ++dir) {
        unsigned k = KSEL, prefix, ceq;
        if (dir == 0)
            suffix_scan_wave<false>(s_hist1, s_scan, t);
        else
            suffix_scan_wave<true>(s_hist1, s_scan, t);
        __syncthreads();
        unsigned sc = s_scan[t], scn = s_scan[t + 1];
        if (sc >= k && scn < k) {
            s_selbin = (unsigned)t;
            s_selk   = k - scn;
            s_seleq  = sc - scn;
        }
        __syncthreads();
        prefix = s_selbin << 24;
        k      = s_selk;
        ceq    = s_seleq;

        for (int shift = 16; shift >= 0; shift -= 8) {
            s_hist2[t] = 0;
            __syncthreads();
            const unsigned mask = 0xFFFFFFFFu << (shift + 8);
#pragma unroll
            for (int j = 0; j < 8; ++j) {
                unsigned kk = dir ? ~key[j] : key[j];
                if ((kk & mask) == prefix)
                    atomicAdd(&s_hist2[(kk >> shift) & 255u], 1u);
            }
            __syncthreads();
            suffix_scan_wave<false>(s_hist2, s_scan, t);
            __syncthreads();
            sc  = s_scan[t];
            scn = s_scan[t + 1];
            if (sc >= k && scn < k) {
                s_selbin = (unsigned)t;
                s_selk   = k - scn;
                s_seleq  = sc - scn;
            }
            __syncthreads();
            prefix |= s_selbin << shift;
            k   = s_selk;
            ceq = s_seleq;
        }
        thr[dir]  = prefix;  // exact 32-bit rank-256 key
        need[dir] = k;       // how many of the equal-valued elems to take
        eqc[dir]  = ceq;     // how many equal-valued elems exist
    }

    // ---- inclusion flags + softmax partial sums ---------------------------
    const float rowmax = s_rowmax, rowmin = s_rowmin;
    float    sumW = 0.f, sumL = 0.f;
    unsigned mW = 0, mL = 0;
#pragma unroll
    for (int j = 0; j < 8; ++j) {
        const unsigned kk  = key[j];
        const unsigned ik  = ~kk;
        const int      idx = (j < 4) ? (4 * t + j) : (1024 + 4 * t + (j - 4));

        bool iw = false;
        if (kk > thr[0]) {
            iw = true;
        } else if (kk == thr[0]) {
            if (eqc[0] == need[0]) {
                iw = true;  // fast path: no boundary tie
            } else {        // rare: rank equals by index (jax top_k stability)
                unsigned r = 0;
                for (int i = 0; i < idx; ++i) r += (f2key(s_vals[i]) == thr[0]);
                iw = (r < need[0]);
            }
        }
        bool il = false;
        if (ik > thr[1]) {
            il = true;
        } else if (ik == thr[1]) {
            if (eqc[1] == need[1]) {
                il = true;
            } else {
                unsigned r = 0;
                for (int i = 0; i < idx; ++i) r += (~f2key(s_vals[i]) == thr[1]);
                il = (r < need[1]);
            }
        }
        if (iw) {
            sumW += __expf(v[j] - rowmax);
            mW |= 1u << j;
        }
        if (il) {
            sumL += __expf(rowmin - v[j]);
            mL |= 1u << j;
        }
    }
#pragma unroll
    for (int off = 32; off; off >>= 1) {
        sumW += __shfl_down(sumW, off);
        sumL += __shfl_down(sumL, off);
    }
    if (lane == 0) {
        s_redf[wave]     = sumW;
        s_redf[4 + wave] = sumL;
    }
    __syncthreads();
    if (t == 0) {
        s_invZW = 1.f / (s_redf[0] + s_redf[1] + s_redf[2] + s_redf[3]);
        s_invZL = 1.f / (s_redf[4] + s_redf[5] + s_redf[6] + s_redf[7]);
    }
    __syncthreads();
    const float izw = s_invZW, izl = s_invZL;

    // ---- write dense outputs (all elements; harness poisons d_out) --------
    float lw[8], sw[8];
#pragma unroll
    for (int j = 0; j < 8; ++j) {
        lw[j] = (mW >> j & 1u) ? __expf(v[j] - rowmax) * izw : 0.f;
        sw[j] = (mL >> j & 1u) ? __expf(rowmin - v[j]) * izl : 0.f;
    }
    float4* lp = (float4*)(out_long + base);
    float4* sp = (float4*)(out_short + base);
    lp[t]      = make_float4(lw[0], lw[1], lw[2], lw[3]);
    lp[t + NT] = make_float4(lw[4], lw[5], lw[6], lw[7]);
    sp[t]      = make_float4(sw[0], sw[1], sw[2], sw[3]);
    sp[t + NT] = make_float4(sw[4], sw[5], sw[6], sw[7]);

    if (t == 0) out_sr[row] = fminf(fmaxf(short_ratio[row], 0.f), 1.f);
}

extern "C" void kernel_launch(void* const* d_in, const int* in_sizes, int n_in,
                              void* d_out, int out_size, void* d_ws,
                              size_t ws_size, hipStream_t stream) {
    const float* scores = (const float*)d_in[0];
    const float* sr     = (const float*)d_in[1];
    const int    B      = in_sizes[1];  // 16384
    float* out       = (float*)d_out;
    float* out_long  = out;
    float* out_short = out + (size_t)B * SDIM;
    float* out_sr    = out + 2 * (size_t)B * SDIM;
    portfolio_kernel<<<B, NT, 0, stream>>>(scores, sr, out_long, out_short,
                                           out_sr);
}

// Round 2
// 383.735 us; speedup vs baseline: 1.1895x; 1.1895x over previous
//
#include <hip/hip_runtime.h>

// PortfolioGenerator: B=16384 rows of S=2048 fp32 scores.
// long = scatter(softmax(top256)), short = scatter(softmax(1-bottom256))
//      = softmax(-bottom256) by shift invariance; plus clipped short_ratio.
//
// R2 design: ONE WAVE PER ROW, zero __syncthreads (wave64 lockstep; per-wave
// LDS regions; DS ops in-order per wave). Exact rank-256 via value-binned
// 256-bin histogram (spreads Gaussian data -> low same-address atomic
// serialization) + exact candidate ranking of the boundary bin by
// (value, index) — matches jax top_k tie stability.

#define NT   256
#define WPB  4      // waves (=rows) per block
#define SDIM 2048
#define KSEL 256u
#define EPL  32     // elements per lane (2048 / 64)
#define CAP  192    // candidate buffer capacity per wave

__device__ __forceinline__ int binOf(float x) {
    int b = (int)__builtin_fmaf(x, 32.f, 128.f);
    return min(max(b, 0), 255);
}

__global__ void __launch_bounds__(NT) portfolio_kernel(
    const float* __restrict__ scores, const float* __restrict__ short_ratio,
    float* __restrict__ out_long, float* __restrict__ out_short,
    float* __restrict__ out_sr) {
    __shared__ unsigned s_hist[WPB][256];
    __shared__ float    s_candV[WPB][CAP];
    __shared__ unsigned s_candI[WPB][CAP];
    __shared__ unsigned s_cnt[WPB];

    const int    t    = threadIdx.x;
    const int    lane = t & 63;
    const int    wv   = t >> 6;
    const int    row  = blockIdx.x * WPB + wv;
    const size_t base = (size_t)row * SDIM;

    // ---- load 32 elems/lane; chunk i*64+lane holds idx = i*256+lane*4+c ---
    const float4* rp = (const float4*)(scores + base);
    float v[EPL];
#pragma unroll
    for (int i = 0; i < 8; ++i) {
        float4 a    = rp[i * 64 + lane];
        v[4 * i + 0] = a.x;
        v[4 * i + 1] = a.y;
        v[4 * i + 2] = a.z;
        v[4 * i + 3] = a.w;
    }

    // ---- row max/min (butterfly; all lanes get result) --------------------
    float vmax = v[0], vmin = v[0];
#pragma unroll
    for (int j = 1; j < EPL; ++j) {
        vmax = fmaxf(vmax, v[j]);
        vmin = fminf(vmin, v[j]);
    }
#pragma unroll
    for (int off = 32; off; off >>= 1) {
        vmax = fmaxf(vmax, __shfl_xor(vmax, off));
        vmin = fminf(vmin, __shfl_xor(vmin, off));
    }

    // ---- value-binned histogram (per-wave, wave-sync, no barriers) --------
    unsigned* hist = s_hist[wv];
    *((uint4*)&hist[lane * 4]) = make_uint4(0u, 0u, 0u, 0u);
#pragma unroll
    for (int j = 0; j < EPL; ++j) atomicAdd(&hist[binOf(v[j])], 1u);

    // ---- scan: lane owns bins 4l..4l+3; find winner & loser bins ----------
    uint4    h   = *((const uint4*)&hist[lane * 4]);
    unsigned p0  = h.x, p1 = p0 + h.y, p2 = p1 + h.z, p3 = p2 + h.w;
    unsigned pre = p3;
#pragma unroll
    for (int off = 1; off < 64; off <<= 1) {
        unsigned x = __shfl_up(pre, off);
        if (lane >= off) pre += x;
    }
    const unsigned before = pre - p3;  // # elems in bins < 4*lane
    // inclusive counts L[c] = # elems in bins <= 4*lane + c - 1 (c=0 => before)
    unsigned L[5] = {before, before + p0, before + p1, before + p2, before + p3};
    const unsigned T = (unsigned)SDIM;

    int      bwLoc = -1, blLoc = -1;
    unsigned needwLoc = 0, CwLoc = 0, needlLoc = 0, ClLoc = 0;
#pragma unroll
    for (int c = 0; c < 4; ++c) {
        const unsigned cnt_b = (c == 0) ? h.x : (c == 1) ? h.y : (c == 2) ? h.z : h.w;
        const unsigned tc = T - L[c], tcn = T - L[c + 1];  // topcnt[b], topcnt[b+1]
        if (tc >= KSEL && tcn < KSEL) {
            bwLoc    = lane * 4 + c;
            needwLoc = KSEL - tcn;
            CwLoc    = cnt_b;
        }
        if (L[c + 1] >= KSEL && L[c] < KSEL) {  // botcnt crossing
            blLoc    = lane * 4 + c;
            needlLoc = KSEL - L[c];
            ClLoc    = cnt_b;
        }
    }
    unsigned long long mW = __ballot(bwLoc >= 0);
    unsigned long long mL = __ballot(blLoc >= 0);
    const int sw = __ffsll(mW) - 1, sl = __ffsll(mL) - 1;
    const int      bw    = __shfl(bwLoc, sw);
    const unsigned needw = (unsigned)__shfl((int)needwLoc, sw);
    const unsigned Cw    = min((unsigned)__shfl((int)CwLoc, sw), (unsigned)CAP);
    const int      bl    = __shfl(blLoc, sl);
    const unsigned needl = (unsigned)__shfl((int)needlLoc, sl);
    const unsigned Cl    = min((unsigned)__shfl((int)ClLoc, sl), (unsigned)CAP);

    float*    candV = s_candV[wv];
    unsigned* candI = s_candI[wv];

    // ---- winner boundary bin: gather + exact rank -> cutoff ---------------
    if (lane == 0) s_cnt[wv] = 0;
#pragma unroll
    for (int j = 0; j < EPL; ++j) {
        if (binOf(v[j]) == bw) {
            unsigned pos = atomicAdd(&s_cnt[wv], 1u);
            if (pos < CAP) {
                candV[pos] = v[j];
                candI[pos] = (unsigned)((j >> 2) * 256 + lane * 4 + (j & 3));
            }
        }
    }
    float    fV = 0.f;
    unsigned fI = 0;
    bool     found = false;
    for (unsigned c = (unsigned)lane; c < Cw; c += 64) {
        const float    pv = candV[c];
        const unsigned pi = candI[c];
        unsigned       r  = 0;
        for (unsigned c2 = 0; c2 < Cw; ++c2) {
            const float    qv = candV[c2];
            const unsigned qi = candI[c2];
            r += (qv > pv) || (qv == pv && qi < pi);
        }
        if (r == needw - 1) { found = true; fV = pv; fI = pi; }
    }
    unsigned long long fm = __ballot(found);
    float    cutVw = INFINITY;
    unsigned cutIw = 0;
    if (fm) {
        const int fl2 = __ffsll(fm) - 1;
        cutVw = __shfl(fV, fl2);
        cutIw = (unsigned)__shfl((int)fI, fl2);
    }

    // ---- loser boundary bin (reuse buffers; same-wave in-order LDS) -------
    if (lane == 0) s_cnt[wv] = 0;
#pragma unroll
    for (int j = 0; j < EPL; ++j) {
        if (binOf(v[j]) == bl) {
            unsigned pos = atomicAdd(&s_cnt[wv], 1u);
            if (pos < CAP) {
                candV[pos] = v[j];
                candI[pos] = (unsigned)((j >> 2) * 256 + lane * 4 + (j & 3));
            }
        }
    }
    fV = 0.f; fI = 0; found = false;
    for (unsigned c = (unsigned)lane; c < Cl; c += 64) {
        const float    pv = candV[c];
        const unsigned pi = candI[c];
        unsigned       r  = 0;
        for (unsigned c2 = 0; c2 < Cl; ++c2) {
            const float    qv = candV[c2];
            const unsigned qi = candI[c2];
            r += (qv < pv) || (qv == pv && qi < pi);
        }
        if (r == needl - 1) { found = true; fV = pv; fI = pi; }
    }
    fm = __ballot(found);
    float    cutVl = -INFINITY;
    unsigned cutIl = 0;
    if (fm) {
        const int fl2 = __ffsll(fm) - 1;
        cutVl = __shfl(fV, fl2);
        cutIl = (unsigned)__shfl((int)fI, fl2);
    }

    // ---- softmax partial sums over selected sets --------------------------
    float sumW = 0.f, sumL = 0.f;
#pragma unroll
    for (int j = 0; j < EPL; ++j) {
        const unsigned idx  = (unsigned)((j >> 2) * 256 + lane * 4 + (j & 3));
        const bool     selw = (v[j] > cutVw) || (v[j] == cutVw && idx <= cutIw);
        const bool     sell = (v[j] < cutVl) || (v[j] == cutVl && idx <= cutIl);
        if (selw) sumW += __expf(v[j] - vmax);
        if (sell) sumL += __expf(vmin - v[j]);
    }
#pragma unroll
    for (int off = 32; off; off >>= 1) {
        sumW += __shfl_xor(sumW, off);
        sumL += __shfl_xor(sumL, off);
    }
    const float izw = 1.f / sumW, izl = 1.f / sumL;

    // ---- dense writes (coalesced float4) ----------------------------------
    float4* lp = (float4*)(out_long + base);
    float4* sp = (float4*)(out_short + base);
#pragma unroll
    for (int i = 0; i < 8; ++i) {
        float lw[4], swt[4];
#pragma unroll
        for (int c = 0; c < 4; ++c) {
            const int      j    = 4 * i + c;
            const unsigned idx  = (unsigned)(i * 256 + lane * 4 + c);
            const bool     selw = (v[j] > cutVw) || (v[j] == cutVw && idx <= cutIw);
            const bool     sell = (v[j] < cutVl) || (v[j] == cutVl && idx <= cutIl);
            lw[c]  = selw ? __expf(v[j] - vmax) * izw : 0.f;
            swt[c] = sell ? __expf(vmin - v[j]) * izl : 0.f;
        }
        lp[i * 64 + lane] = make_float4(lw[0], lw[1], lw[2], lw[3]);
        sp[i * 64 + lane] = make_float4(swt[0], swt[1], swt[2], swt[3]);
    }
    if (lane == 0) out_sr[row] = fminf(fmaxf(short_ratio[row], 0.f), 1.f);
}

extern "C" void kernel_launch(void* const* d_in, const int* in_sizes, int n_in,
                              void* d_out, int out_size, void* d_ws,
                              size_t ws_size, hipStream_t stream) {
    const float* scores = (const float*)d_in[0];
    const float* sr     = (const float*)d_in[1];
    const int    B      = in_sizes[1];  // 16384
    float* out       = (float*)d_out;
    float* out_long  = out;
    float* out_short = out + (size_t)B * SDIM;
    float* out_sr    = out + 2 * (size_t)B * SDIM;
    portfolio_kernel<<<B / WPB, NT, 0, stream>>>(scores, sr, out_long,
                                                 out_short, out_sr);
}